// Round 3
// baseline (97.266 us; speedup 1.0000x reference)
//
#include <hip/hip_runtime.h>

#define NSLICE 6
#define NPIX   4096
#define M      20            // Fourier frequencies 1..M
#define TPB    512
#define PXT    (NPIX / TPB)  // 8 pixels per thread

// K(d) = exp(-(d/sigma)^2), sigma=0.1, approximated on d in [-1,1] by
//   K(d) ~= c0 + sum_{m=1..M} 2*c_m*cos(pi*m*d),  c_m = (sigma*sqrt(pi)/2)*exp(-(pi*m*sigma)^2/4)
// Truncation tail at M=20: ~5e-6 absolute; periodization error ~exp(-100).
#define C0      0.088622693f   // sigma*sqrt(pi)/2
#define TWO_C0  0.177245385f
#define AEXP    0.024674011f   // (pi*sigma)^2 / 4
#define DEN0    362.99854f     // C0 * NPIX

__global__ __launch_bounds__(TPB, 2) void bilateral_fourier(
        const float* __restrict__ x, float* __restrict__ out) {
    __shared__ float partial[64][81];          // per-8-lane-group partials (~21 KB)
    __shared__ __align__(16) float fin[(M + 1) * 4];

    const int tid = threadIdx.x;
    const int s   = blockIdx.x;
    const float* xs = x + s * NPIX;

    // Load 8 pixels/thread as two float4 (coalesced 16B).
    const float4* x4 = (const float4*)xs;
    float4 a = x4[tid], b = x4[TPB + tid];
    float px[PXT] = {a.x, a.y, a.z, a.w, b.x, b.y, b.z, b.w};
    float pc[PXT], ps[PXT];

    // ---- Phase 1: moments Sc_m, Ss_m, Tc_m, Ts_m, X over this thread's pixels.
    float Sc[M], Ss[M], Tc[M], Ts[M], X = 0.f;
    #pragma unroll
    for (int m = 0; m < M; ++m) { Sc[m] = 0.f; Ss[m] = 0.f; Tc[m] = 0.f; Ts[m] = 0.f; }

    #pragma unroll
    for (int j = 0; j < PXT; ++j) {
        float v = px[j];
        float s1, c1;
        sincospif(v, &s1, &c1);                 // sin(pi v), cos(pi v)
        pc[j] = c1; ps[j] = s1;
        X += v;
        float tc = c1 + c1;
        float cm2 = 1.f, sm2 = 0.f, cm1 = c1, sm1 = s1;
        Sc[0] += c1; Ss[0] += s1;
        Tc[0] = fmaf(v, c1, Tc[0]); Ts[0] = fmaf(v, s1, Ts[0]);
        #pragma unroll
        for (int m = 1; m < M; ++m) {           // Chebyshev recurrence
            float cn = fmaf(tc, cm1, -cm2);
            float sn = fmaf(tc, sm1, -sm2);
            cm2 = cm1; cm1 = cn; sm2 = sm1; sm1 = sn;
            Sc[m] += cn; Ss[m] += sn;
            Tc[m] = fmaf(v, cn, Tc[m]); Ts[m] = fmaf(v, sn, Ts[m]);
        }
    }

    // 3-level butterfly within 8-lane groups, then LDS tree.
    #pragma unroll
    for (int off = 1; off < 8; off <<= 1) {
        #pragma unroll
        for (int m = 0; m < M; ++m) {
            Sc[m] += __shfl_xor(Sc[m], off);
            Ss[m] += __shfl_xor(Ss[m], off);
            Tc[m] += __shfl_xor(Tc[m], off);
            Ts[m] += __shfl_xor(Ts[m], off);
        }
        X += __shfl_xor(X, off);
    }
    const int grp = tid >> 3;
    if ((tid & 7) == 0) {
        #pragma unroll
        for (int m = 0; m < M; ++m) {
            partial[grp][m]      = Sc[m];
            partial[grp][20 + m] = Ss[m];
            partial[grp][40 + m] = Tc[m];
            partial[grp][60 + m] = Ts[m];
        }
        partial[grp][80] = X;
    }
    __syncthreads();

    if (tid < 81) {
        float sum = 0.f;
        #pragma unroll 8
        for (int g = 0; g < 64; ++g) sum += partial[g][tid];
        if (tid == 80) {
            fin[0] = DEN0;             // c0 * N   (den constant term)
            fin[1] = C0 * sum;         // c0 * X   (num constant term)
            fin[2] = 0.f; fin[3] = 0.f;
        } else {
            int m    = tid % 20 + 1;   // frequency 1..20
            int kind = tid / 20;       // 0:Sc 1:Ss 2:Tc 3:Ts
            float coef = TWO_C0 * __expf(-AEXP * (float)(m * m));
            fin[m * 4 + kind] = coef * sum;
        }
    }
    __syncthreads();

    // ---- Phase 2: per-pixel recombination, all register-resident.
    float4 F[M + 1];
    const float4* f4 = (const float4*)fin;
    #pragma unroll
    for (int m = 0; m <= M; ++m) F[m] = f4[m];

    float res[PXT];
    #pragma unroll
    for (int j = 0; j < PXT; ++j) {
        float c1 = pc[j], s1 = ps[j];
        float tc = c1 + c1;
        float den = F[0].x, num = F[0].y;
        den = fmaf(c1, F[1].x, den); den = fmaf(s1, F[1].y, den);
        num = fmaf(c1, F[1].z, num); num = fmaf(s1, F[1].w, num);
        float cm2 = 1.f, sm2 = 0.f, cm1 = c1, sm1 = s1;
        #pragma unroll
        for (int m = 2; m <= M; ++m) {
            float cn = fmaf(tc, cm1, -cm2);
            float sn = fmaf(tc, sm1, -sm2);
            cm2 = cm1; cm1 = cn; sm2 = sm1; sm1 = sn;
            den = fmaf(cn, F[m].x, den); den = fmaf(sn, F[m].y, den);
            num = fmaf(cn, F[m].z, num); num = fmaf(sn, F[m].w, num);
        }
        res[j] = num / den;
    }

    float4* o4 = (float4*)(out + s * NPIX);
    o4[tid]       = make_float4(res[0], res[1], res[2], res[3]);
    o4[TPB + tid] = make_float4(res[4], res[5], res[6], res[7]);
}

extern "C" void kernel_launch(void* const* d_in, const int* in_sizes, int n_in,
                              void* d_out, int out_size, void* d_ws, size_t ws_size,
                              hipStream_t stream) {
    const float* x = (const float*)d_in[0];
    float* out = (float*)d_out;
    bilateral_fourier<<<dim3(NSLICE), dim3(TPB), 0, stream>>>(x, out);
}

// Round 4
// 94.143 us; speedup vs baseline: 1.0332x; 1.0332x over previous
//
#include <hip/hip_runtime.h>

#define NSLICE 6
#define NPIX   4096
#define M      20            // Fourier frequencies 1..M
#define TPB    512
#define PXT    (NPIX / TPB)  // 8 pixels per thread

// K(d) = exp(-(d/sigma)^2), sigma=0.1, approximated on d in [-1,1] by
//   K(d) ~= c0 + sum_{m=1..M} 2*c_m*cos(pi*m*d),  c_m = (sigma*sqrt(pi)/2)*exp(-(pi*m*sigma)^2/4)
// Truncation tail at M=20: ~5e-6 absolute; periodization error ~exp(-100).
#define C0      0.088622693f   // sigma*sqrt(pi)/2
#define TWO_C0  0.177245385f
#define AEXP    0.024674011f   // (pi*sigma)^2 / 4
#define DEN0    362.99854f     // C0 * NPIX

// sin(pi*v), cos(pi*v) via raw v_sin_f32/v_cos_f32 (input in revolutions:
// D = sin(2*pi*x)). No OCML call -> no caller-save spill of the 80 live
// moment accumulators (round-3 pathology: 5.2 MB scratch traffic, 54 us).
__device__ __forceinline__ void sincos_pi(float v, float* s, float* c) {
#if defined(__has_builtin) && __has_builtin(__builtin_amdgcn_sinf)
    *s = __builtin_amdgcn_sinf(0.5f * v);
    *c = __builtin_amdgcn_cosf(0.5f * v);
#else
    *s = __sinf(3.14159265358979f * v);
    *c = __cosf(3.14159265358979f * v);
#endif
}

__global__ __launch_bounds__(TPB) void bilateral_fourier(
        const float* __restrict__ x, float* __restrict__ out) {
    __shared__ float partial[64][81];          // per-8-lane-group partials (~21 KB)
    __shared__ __align__(16) float fin[(M + 1) * 4];

    const int tid = threadIdx.x;
    const int s   = blockIdx.x;
    const float* xs = x + s * NPIX;

    // Load 8 pixels/thread as two float4 (coalesced 16B).
    const float4* x4 = (const float4*)xs;
    float4 a = x4[tid], b = x4[TPB + tid];
    float px[PXT] = {a.x, a.y, a.z, a.w, b.x, b.y, b.z, b.w};
    float pc[PXT], ps[PXT];

    // ---- Phase 1: moments Sc_m, Ss_m, Tc_m, Ts_m, X over this thread's pixels.
    float Sc[M], Ss[M], Tc[M], Ts[M], X = 0.f;
    #pragma unroll
    for (int m = 0; m < M; ++m) { Sc[m] = 0.f; Ss[m] = 0.f; Tc[m] = 0.f; Ts[m] = 0.f; }

    #pragma unroll
    for (int j = 0; j < PXT; ++j) {
        float v = px[j];
        float s1, c1;
        sincos_pi(v, &s1, &c1);                 // inline v_sin/v_cos, no call
        pc[j] = c1; ps[j] = s1;
        X += v;
        float tc = c1 + c1;
        float cm2 = 1.f, sm2 = 0.f, cm1 = c1, sm1 = s1;
        Sc[0] += c1; Ss[0] += s1;
        Tc[0] = fmaf(v, c1, Tc[0]); Ts[0] = fmaf(v, s1, Ts[0]);
        #pragma unroll
        for (int m = 1; m < M; ++m) {           // Chebyshev recurrence
            float cn = fmaf(tc, cm1, -cm2);
            float sn = fmaf(tc, sm1, -sm2);
            cm2 = cm1; cm1 = cn; sm2 = sm1; sm1 = sn;
            Sc[m] += cn; Ss[m] += sn;
            Tc[m] = fmaf(v, cn, Tc[m]); Ts[m] = fmaf(v, sn, Ts[m]);
        }
    }

    // 3-level butterfly within 8-lane groups, then LDS tree.
    #pragma unroll
    for (int off = 1; off < 8; off <<= 1) {
        #pragma unroll
        for (int m = 0; m < M; ++m) {
            Sc[m] += __shfl_xor(Sc[m], off);
            Ss[m] += __shfl_xor(Ss[m], off);
            Tc[m] += __shfl_xor(Tc[m], off);
            Ts[m] += __shfl_xor(Ts[m], off);
        }
        X += __shfl_xor(X, off);
    }
    const int grp = tid >> 3;
    if ((tid & 7) == 0) {
        #pragma unroll
        for (int m = 0; m < M; ++m) {
            partial[grp][m]      = Sc[m];
            partial[grp][20 + m] = Ss[m];
            partial[grp][40 + m] = Tc[m];
            partial[grp][60 + m] = Ts[m];
        }
        partial[grp][80] = X;
    }
    __syncthreads();

    if (tid < 81) {
        float sum = 0.f;
        #pragma unroll 8
        for (int g = 0; g < 64; ++g) sum += partial[g][tid];
        if (tid == 80) {
            fin[0] = DEN0;             // c0 * N   (den constant term)
            fin[1] = C0 * sum;         // c0 * X   (num constant term)
            fin[2] = 0.f; fin[3] = 0.f;
        } else {
            int m    = tid % 20 + 1;   // frequency 1..20
            int kind = tid / 20;       // 0:Sc 1:Ss 2:Tc 3:Ts
            float coef = TWO_C0 * __expf(-AEXP * (float)(m * m));
            fin[m * 4 + kind] = coef * sum;
        }
    }
    __syncthreads();

    // ---- Phase 2: per-pixel recombination, all register-resident.
    float4 F[M + 1];
    const float4* f4 = (const float4*)fin;
    #pragma unroll
    for (int m = 0; m <= M; ++m) F[m] = f4[m];

    float res[PXT];
    #pragma unroll
    for (int j = 0; j < PXT; ++j) {
        float c1 = pc[j], s1 = ps[j];
        float tc = c1 + c1;
        float den = F[0].x, num = F[0].y;
        den = fmaf(c1, F[1].x, den); den = fmaf(s1, F[1].y, den);
        num = fmaf(c1, F[1].z, num); num = fmaf(s1, F[1].w, num);
        float cm2 = 1.f, sm2 = 0.f, cm1 = c1, sm1 = s1;
        #pragma unroll
        for (int m = 2; m <= M; ++m) {
            float cn = fmaf(tc, cm1, -cm2);
            float sn = fmaf(tc, sm1, -sm2);
            cm2 = cm1; cm1 = cn; sm2 = sm1; sm1 = sn;
            den = fmaf(cn, F[m].x, den); den = fmaf(sn, F[m].y, den);
            num = fmaf(cn, F[m].z, num); num = fmaf(sn, F[m].w, num);
        }
        res[j] = num / den;
    }

    float4* o4 = (float4*)(out + s * NPIX);
    o4[tid]       = make_float4(res[0], res[1], res[2], res[3]);
    o4[TPB + tid] = make_float4(res[4], res[5], res[6], res[7]);
}

extern "C" void kernel_launch(void* const* d_in, const int* in_sizes, int n_in,
                              void* d_out, int out_size, void* d_ws, size_t ws_size,
                              hipStream_t stream) {
    const float* x = (const float*)d_in[0];
    float* out = (float*)d_out;
    bilateral_fourier<<<dim3(NSLICE), dim3(TPB), 0, stream>>>(x, out);
}

// Round 5
// 54.463 us; speedup vs baseline: 1.7859x; 1.7286x over previous
//
#include <hip/hip_runtime.h>

#define NSLICE 6
#define NPIX   4096
#define M      20             // Fourier frequencies 1..M

// K(d) = exp(-(d/sigma)^2), sigma=0.1, on d in [-1,1]:
//   K(d) ~= c0 + sum_{m=1..M} 2*c_m*cos(pi*m*d),
//   c_m = (sigma*sqrt(pi)/2)*exp(-(pi*m*sigma)^2/4)
// Tail at M=20 ~5e-6 abs; periodization ~exp(-100).
#define C0         0.088622693f    // sigma*sqrt(pi)/2
#define TWO_C0     0.177245385f
#define AEXP_LOG2  0.035597112f    // (pi*sigma)^2/4 * log2(e)
#define DEN0       362.99854f      // C0 * NPIX

// ---------------------------------------------------------------------------
// K1: one block per (frequency m, slice). 256 threads x 16 px. Only 5 live
// accumulators/thread -> no spill (round-4 pathology was 80+ accs spilling).
// sin(pi*m*v) = v_sin(0.5*m*v revolutions), computed directly per m — no
// recurrence, so frequencies parallelize across blocks.
// ws layout: ws[(s*(M+1) + m)*4 + {0:Sc,1:Ss,2:Tc,3:Ts}], m=0 slot = const terms.
__global__ __launch_bounds__(256) void moments_kernel(
        const float* __restrict__ x, float* __restrict__ ws) {
    const int mi = blockIdx.x;           // 0..19 -> frequency mi+1
    const int s  = blockIdx.y;
    const float fm = (float)(mi + 1);
    const int tid = threadIdx.x;
    const float4* x4 = (const float4*)(x + s * NPIX);

    float Sc = 0.f, Ss = 0.f, Tc = 0.f, Ts = 0.f, X = 0.f;
    #pragma unroll
    for (int j = 0; j < NPIX / 4 / 256; ++j) {       // 4 iters, coalesced 16B
        float4 v4 = x4[j * 256 + tid];
        float vv[4] = {v4.x, v4.y, v4.z, v4.w};
        #pragma unroll
        for (int k = 0; k < 4; ++k) {
            float v   = vv[k];
            float arg = 0.5f * fm * v;               // revolutions
            float sn  = __builtin_amdgcn_sinf(arg);  // v_sin_f32
            float cn  = __builtin_amdgcn_cosf(arg);  // v_cos_f32
            Sc += cn;  Ss += sn;
            Tc = fmaf(v, cn, Tc);
            Ts = fmaf(v, sn, Ts);
            X += v;
        }
    }

    #pragma unroll
    for (int off = 1; off < 64; off <<= 1) {
        Sc += __shfl_xor(Sc, off);  Ss += __shfl_xor(Ss, off);
        Tc += __shfl_xor(Tc, off);  Ts += __shfl_xor(Ts, off);
        X  += __shfl_xor(X,  off);
    }
    __shared__ float red[4][5];
    const int w = tid >> 6;
    if ((tid & 63) == 0) {
        red[w][0] = Sc; red[w][1] = Ss; red[w][2] = Tc; red[w][3] = Ts; red[w][4] = X;
    }
    __syncthreads();
    if (tid == 0) {
        float sc = 0.f, ss = 0.f, tc = 0.f, ts = 0.f, xx = 0.f;
        #pragma unroll
        for (int ww = 0; ww < 4; ++ww) {
            sc += red[ww][0]; ss += red[ww][1]; tc += red[ww][2];
            ts += red[ww][3]; xx += red[ww][4];
        }
        float coef = TWO_C0 * __builtin_amdgcn_exp2f(-AEXP_LOG2 * fm * fm);
        float* f = ws + (s * (M + 1) + (mi + 1)) * 4;
        f[0] = coef * sc;  f[1] = coef * ss;
        f[2] = coef * tc;  f[3] = coef * ts;
        if (mi == 0) {                    // constant terms, written once/slice
            float* f0 = ws + s * (M + 1) * 4;
            f0[0] = DEN0;  f0[1] = C0 * xx;  f0[2] = 0.f;  f0[3] = 0.f;
        }
    }
}

// ---------------------------------------------------------------------------
// K2: one pixel per thread, 48 blocks x 512. F table staged in LDS and read
// per recurrence step (same-address broadcast, conflict-free). ~25 live VGPRs.
__global__ __launch_bounds__(512) void recombine_kernel(
        const float* __restrict__ x, const float* __restrict__ ws,
        float* __restrict__ out) {
    const int s = blockIdx.y;
    const int p = blockIdx.x * 512 + threadIdx.x;
    __shared__ __align__(16) float fin[(M + 1) * 4];
    if (threadIdx.x < (M + 1) * 4)
        fin[threadIdx.x] = ws[s * (M + 1) * 4 + threadIdx.x];
    __syncthreads();

    const float v  = x[s * NPIX + p];
    const float s1 = __builtin_amdgcn_sinf(0.5f * v);   // sin(pi*v)
    const float c1 = __builtin_amdgcn_cosf(0.5f * v);   // cos(pi*v)
    const float4* F = (const float4*)fin;

    float4 f0 = F[0], f1 = F[1];
    float den = f0.x, num = f0.y;
    den = fmaf(c1, f1.x, den);  den = fmaf(s1, f1.y, den);
    num = fmaf(c1, f1.z, num);  num = fmaf(s1, f1.w, num);

    const float tc = c1 + c1;
    float cm2 = 1.f, sm2 = 0.f, cm1 = c1, sm1 = s1;
    #pragma unroll
    for (int m = 2; m <= M; ++m) {        // Chebyshev recurrence in xp only
        float cn = fmaf(tc, cm1, -cm2);
        float sn = fmaf(tc, sm1, -sm2);
        cm2 = cm1; cm1 = cn; sm2 = sm1; sm1 = sn;
        float4 f = F[m];                  // ds_read_b128 broadcast
        den = fmaf(cn, f.x, den);  den = fmaf(sn, f.y, den);
        num = fmaf(cn, f.z, num);  num = fmaf(sn, f.w, num);
    }
    out[s * NPIX + p] = num / den;
}

extern "C" void kernel_launch(void* const* d_in, const int* in_sizes, int n_in,
                              void* d_out, int out_size, void* d_ws, size_t ws_size,
                              hipStream_t stream) {
    const float* x = (const float*)d_in[0];
    float* out = (float*)d_out;
    float* ws  = (float*)d_ws;            // 6*21*4 floats = 2016 B used
    moments_kernel<<<dim3(M, NSLICE), dim3(256), 0, stream>>>(x, ws);
    recombine_kernel<<<dim3(NPIX / 512, NSLICE), dim3(512), 0, stream>>>(x, ws, out);
}